// Round 2
// baseline (136.186 us; speedup 1.0000x reference)
//
#include <hip/hip_runtime.h>

typedef unsigned short u16;
typedef unsigned int   u32;
typedef __attribute__((ext_vector_type(8))) short bf16x8;
typedef __attribute__((ext_vector_type(4))) float f32x4;

#define BB 2
#define SS 4096
#define DD 768
#define HH 12
#define FF 3072
#define NTOK 8192

__device__ __forceinline__ float bf2f(u16 u) {
  u32 x = ((u32)u) << 16;
  return __uint_as_float(x);
}
__device__ __forceinline__ u16 f2bf(float f) {
  u32 x = __float_as_uint(f);
  x = x + 0x7FFFu + ((x >> 16) & 1u);
  return (u16)(x >> 16);
}
__device__ __forceinline__ float gelu_f(float v) {
  return 0.5f * v * (1.0f + erff(v * 0.70710678118654752f));
}

template<bool MAXOP>
__device__ __forceinline__ float blk_reduce(float v, float* sbuf) {
  #pragma unroll
  for (int o = 32; o > 0; o >>= 1) {
    float t = __shfl_xor(v, o, 64);
    v = MAXOP ? fmaxf(v, t) : (v + t);
  }
  int wave = threadIdx.x >> 6;
  int nw = blockDim.x >> 6;
  __syncthreads();
  if ((threadIdx.x & 63) == 0) sbuf[wave] = v;
  __syncthreads();
  float r = sbuf[0];
  for (int i = 1; i < nw; i++) r = MAXOP ? fmaxf(r, sbuf[i]) : (r + sbuf[i]);
  return r;
}

// ---- transpose + f32->bf16 convert: WT[n][k] = bf16(W[k][n]), 768x768 ----
__global__ __launch_bounds__(256) void transcvt(const float* __restrict__ W, u16* __restrict__ WT) {
  __shared__ float t[32][33];
  int n0 = blockIdx.x * 32, k0 = blockIdx.y * 32;
  int tx = threadIdx.x & 31, ty = threadIdx.x >> 5; // 32x8
  #pragma unroll
  for (int i = 0; i < 32; i += 8)
    t[ty + i][tx] = W[(size_t)(k0 + ty + i) * DD + n0 + tx];
  __syncthreads();
  #pragma unroll
  for (int i = 0; i < 32; i += 8)
    WT[(size_t)(n0 + ty + i) * DD + k0 + tx] = f2bf(t[tx][ty + i]);
}

// ---- seed accumulators with biases, build gidx (GLOBAL token rows: b*S + s) ----
__global__ void seed_k(const int* sp, const int* ep, const float* bq, const float* bo,
                       const float* b1, const float* b2,
                       float* qg, float* oa, float* f1, float* f2, int* gidx) {
  int tid = threadIdx.x;
  if (tid < 4) {
    int b = tid >> 1;
    int s = (tid & 1) ? ep[b] : sp[b];
    gidx[tid] = b * SS + s;   // global row into the 8192-token x buffer
  }
  for (int i = tid; i < DD; i += 256) {
    float vq = bq[i], vo = bo[i], v2 = b2[i];
    #pragma unroll
    for (int r = 0; r < 4; r++) {
      qg[r * DD + i] = vq; oa[r * DD + i] = vo; f2[r * DD + i] = v2;
    }
  }
  for (int i = tid; i < FF; i += 256) {
    float v1 = b1[i];
    #pragma unroll
    for (int r = 0; r < 4; r++) f1[r * FF + i] = v1;
  }
}

// ---- x = LN(emb[sent] + pos) -> bf16, one block per token ----
__global__ __launch_bounds__(256) void embed_ln_k(const int* __restrict__ sent,
    const float* __restrict__ emb, const float* __restrict__ pos,
    const float* __restrict__ g, const float* __restrict__ be, u16* __restrict__ xout) {
  __shared__ float sbuf[8];
  int tok = blockIdx.x;
  int s = tok & (SS - 1);
  int row = sent[tok];
  float v[3];
  float sum = 0.f, sq = 0.f;
  #pragma unroll
  for (int i = 0; i < 3; i++) {
    int d = threadIdx.x + i * 256;
    float x = emb[(size_t)row * DD + d] + pos[(size_t)s * DD + d];
    v[i] = x; sum += x; sq += x * x;
  }
  sum = blk_reduce<false>(sum, sbuf);
  sq  = blk_reduce<false>(sq, sbuf);
  float mean = sum * (1.f / DD);
  float var  = sq * (1.f / DD) - mean * mean;
  float rstd = rsqrtf(var + 1e-5f);
  #pragma unroll
  for (int i = 0; i < 3; i++) {
    int d = threadIdx.x + i * 256;
    xout[(size_t)tok * DD + d] = f2bf((v[i] - mean) * rstd * g[d] + be[d]);
  }
}

// ---- C[M,768] = bf16( A[M,768](bf16) @ Bt^T + bias ), Bt is [n][k] bf16 ----
__global__ __launch_bounds__(256) void gemm_bias(const u16* __restrict__ A,
    const u16* __restrict__ Bt, const float* __restrict__ bias, u16* __restrict__ C) {
  const int K = DD, N = DD;
  int m0 = blockIdx.x * 128;
  int n0 = blockIdx.y * 128;
  __shared__ u16 As[128][40];
  __shared__ u16 Bs[128][40];
  int tid = threadIdx.x;
  int lane = tid & 63, wave = tid >> 6;
  int wr = wave >> 1, wc = wave & 1;
  f32x4 acc[4][4] = {};
  int sr = tid >> 1;
  int sc = (tid & 1) * 16;
  int fr = lane & 15, fk = (lane >> 4) * 8;
  for (int k0 = 0; k0 < K; k0 += 32) {
    const u16* ag = A + (size_t)(m0 + sr) * K + k0 + sc;
    const u16* bg = Bt + (size_t)(n0 + sr) * K + k0 + sc;
    uint4 a0 = *(const uint4*)(ag);
    uint4 a1 = *(const uint4*)(ag + 8);
    uint4 b0 = *(const uint4*)(bg);
    uint4 b1v = *(const uint4*)(bg + 8);
    __syncthreads();
    *(uint4*)(&As[sr][sc])     = a0;
    *(uint4*)(&As[sr][sc + 8]) = a1;
    *(uint4*)(&Bs[sr][sc])     = b0;
    *(uint4*)(&Bs[sr][sc + 8]) = b1v;
    __syncthreads();
    bf16x8 af[4], bf[4];
    #pragma unroll
    for (int i = 0; i < 4; i++)
      af[i] = *(const bf16x8*)(&As[wr * 64 + i * 16 + fr][fk]);
    #pragma unroll
    for (int j = 0; j < 4; j++)
      bf[j] = *(const bf16x8*)(&Bs[wc * 64 + j * 16 + fr][fk]);
    #pragma unroll
    for (int i = 0; i < 4; i++)
      #pragma unroll
      for (int j = 0; j < 4; j++)
        acc[i][j] = __builtin_amdgcn_mfma_f32_16x16x32_bf16(af[i], bf[j], acc[i][j], 0, 0, 0);
  }
  int cr = (lane >> 4) * 4;
  int cc = lane & 15;
  #pragma unroll
  for (int i = 0; i < 4; i++) {
    #pragma unroll
    for (int j = 0; j < 4; j++) {
      int col = n0 + wc * 64 + j * 16 + cc;
      float bvv = bias[col];
      int rowb = m0 + wr * 64 + i * 16 + cr;
      #pragma unroll
      for (int r = 0; r < 4; r++) {
        float v = acc[i][j][r] + bvv;
        C[(size_t)(rowb + r) * N + col] = f2bf(v);
      }
    }
  }
}

// ---- generic 4-row batched matvec, split-K atomics: acc[r,n] += sum_k in[r,k]*W[k,n] ----
__global__ __launch_bounds__(256) void matvec4(const float* __restrict__ W,
    const float* __restrict__ inF, const u16* __restrict__ inB, const int* __restrict__ gidx,
    float* __restrict__ acc, int K, int N, int kchunk, int mode) {
  __shared__ float s_in[4 * 256];
  int n = blockIdx.x * 256 + threadIdx.x;
  int k0 = blockIdx.y * kchunk;
  for (int idx = threadIdx.x; idx < 4 * kchunk; idx += 256) {
    int r = idx / kchunk, kk = idx - r * kchunk;
    float vv;
    if (mode == 1) vv = bf2f(inB[(size_t)gidx[r] * K + k0 + kk]);
    else vv = inF[(size_t)r * K + k0 + kk];
    if (mode == 2) vv = gelu_f(vv);
    s_in[r * 256 + kk] = vv;
  }
  __syncthreads();
  float a0 = 0.f, a1 = 0.f, a2 = 0.f, a3 = 0.f;
  for (int kk = 0; kk < kchunk; kk++) {
    float w = W[(size_t)(k0 + kk) * N + n];
    a0 += s_in[kk] * w;
    a1 += s_in[256 + kk] * w;
    a2 += s_in[512 + kk] * w;
    a3 += s_in[768 + kk] * w;
  }
  atomicAdd(&acc[n], a0);
  atomicAdd(&acc[N + n], a1);
  atomicAdd(&acc[2 * N + n], a2);
  atomicAdd(&acc[3 * N + n], a3);
}

// ---- global attention partial: per (s-chunk, h, bg) -> (m, sumexp, ov[64]) ----
__global__ __launch_bounds__(256) void gattn_part(const u16* __restrict__ kb,
    const u16* __restrict__ vb, const float* __restrict__ qg, const int* __restrict__ sent,
    float* __restrict__ part) {
  int sc = blockIdx.x, h = blockIdx.y, bg = blockIdx.z;
  int b = bg >> 1;
  __shared__ float qs[64];
  __shared__ float pbuf[256];
  __shared__ float ovred[4][64];
  __shared__ float sbuf[8];
  int tid = threadIdx.x;
  if (tid < 64) qs[tid] = qg[bg * DD + h * 64 + tid];
  __syncthreads();
  int s = sc * 256 + tid;
  size_t rowoff = ((size_t)(b * SS + s)) * DD + h * 64;
  const uint4* kp = (const uint4*)(kb + rowoff);
  float dot = 0.f;
  #pragma unroll
  for (int c = 0; c < 8; c++) {
    uint4 u = kp[c];
    u32 vals[4] = {u.x, u.y, u.z, u.w};
    #pragma unroll
    for (int t = 0; t < 4; t++) {
      float lo = __uint_as_float(vals[t] << 16);
      float hi = __uint_as_float(vals[t] & 0xFFFF0000u);
      dot += qs[c * 8 + t * 2] * lo + qs[c * 8 + t * 2 + 1] * hi;
    }
  }
  float score = (sent[b * SS + s] != 1) ? dot * 0.125f : -1e9f;
  float m = blk_reduce<true>(score, sbuf);
  float p = expf(score - m);
  float psum = blk_reduce<false>(p, sbuf);
  pbuf[tid] = p;
  __syncthreads();
  int d = tid & 63, grp = tid >> 6;
  float a = 0.f;
  for (int j = 0; j < 64; j++) {
    int ss = grp * 64 + j;
    a += pbuf[ss] * bf2f(vb[((size_t)(b * SS + sc * 256 + ss)) * DD + h * 64 + d]);
  }
  ovred[grp][d] = a;
  __syncthreads();
  float* pp = part + (((size_t)bg * HH + h) * 16 + sc) * 66;
  if (tid == 0) { pp[0] = m; pp[1] = psum; }
  if (tid < 64) {
    float o = ovred[0][tid] + ovred[1][tid] + ovred[2][tid] + ovred[3][tid];
    pp[2 + tid] = o;
  }
}

// ---- combine partials -> og[bg, h*64+d] ----
__global__ __launch_bounds__(64) void gattn_comb(const float* __restrict__ part, float* __restrict__ og) {
  int h = blockIdx.x, bg = blockIdx.y;
  int tid = threadIdx.x; // 64
  const float* pp = part + (((size_t)bg * HH + h) * 16) * 66;
  float M = -1e30f;
  for (int c = 0; c < 16; c++) M = fmaxf(M, pp[c * 66]);
  float Ssum = 0.f, o = 0.f;
  for (int c = 0; c < 16; c++) {
    float e = expf(pp[c * 66] - M);
    Ssum += pp[c * 66 + 1] * e;
    o += pp[c * 66 + 2 + tid] * e;
  }
  og[bg * DD + h * 64 + tid] = o / Ssum;
}

// ---- 4-row layernorm: out[r] = LN(in1 + in2)  (in1 = bf16 x[gidx[r]] or f32 rows) ----
__global__ __launch_bounds__(256) void ln4_k(const u16* __restrict__ xb, const int* __restrict__ gidx,
    const float* __restrict__ in1f, const float* __restrict__ in2,
    const float* __restrict__ g, const float* __restrict__ be, float* __restrict__ outp) {
  __shared__ float sbuf[8];
  int r = blockIdx.x;
  float v[3];
  float sum = 0.f, sq = 0.f;
  #pragma unroll
  for (int i = 0; i < 3; i++) {
    int d = threadIdx.x + i * 256;
    float t;
    if (xb) t = bf2f(xb[(size_t)gidx[r] * DD + d]);
    else    t = in1f[r * DD + d];
    t += in2[r * DD + d];
    v[i] = t; sum += t; sq += t * t;
  }
  sum = blk_reduce<false>(sum, sbuf);
  sq  = blk_reduce<false>(sq, sbuf);
  float mean = sum * (1.f / DD);
  float var  = sq * (1.f / DD) - mean * mean;
  float rstd = rsqrtf(var + 1e-5f);
  #pragma unroll
  for (int i = 0; i < 3; i++) {
    int d = threadIdx.x + i * 256;
    outp[r * DD + d] = (v[i] - mean) * rstd * g[d] + be[d];
  }
}

// ---- logits[b,j] = mention[b] . ex[j], one block per j ----
__global__ __launch_bounds__(256) void logits_k(const float* __restrict__ hws,
    const float* __restrict__ ex, float* __restrict__ out) {
  __shared__ float sbuf[8];
  int j = blockIdx.x;
  const float* er = ex + (size_t)j * 1536;
  float d0 = 0.f, d1 = 0.f;
  for (int c = threadIdx.x; c < 768; c += 256) {
    float e0 = er[c], e1 = er[768 + c];
    d0 += hws[c] * e0 + hws[768 + c] * e1;
    d1 += hws[1536 + c] * e0 + hws[2304 + c] * e1;
  }
  d0 = blk_reduce<false>(d0, sbuf);
  d1 = blk_reduce<false>(d1, sbuf);
  if (threadIdx.x == 0) { out[j] = d0; out[128 + j] = d1; }
}

// ---- loss = -sum_b logsoftmax(logits[b])[label_b] ----
__global__ __launch_bounds__(128) void loss_k(const float* __restrict__ lg,
    const int* __restrict__ labels, float* __restrict__ out) {
  __shared__ float sbuf[8];
  int tid = threadIdx.x; // 128
  float v0 = lg[tid], v1 = lg[128 + tid];
  float m0 = blk_reduce<true>(v0, sbuf);
  float m1 = blk_reduce<true>(v1, sbuf);
  float s0 = blk_reduce<false>(expf(v0 - m0), sbuf);
  float s1 = blk_reduce<false>(expf(v1 - m1), sbuf);
  if (tid == 0) {
    float lp0 = lg[labels[0]] - m0 - logf(s0);
    float lp1 = lg[128 + labels[1]] - m1 - logf(s1);
    out[256] = -(lp0 + lp1);
  }
}

extern "C" void kernel_launch(void* const* d_in, const int* in_sizes, int n_in,
                              void* d_out, int out_size, void* d_ws, size_t ws_size,
                              hipStream_t stream) {
  const int*   sent = (const int*)d_in[0];
  const int*   sp   = (const int*)d_in[1];
  const int*   ep   = (const int*)d_in[2];
  const int*   lab  = (const int*)d_in[3];
  const float* emb  = (const float*)d_in[4];
  const float* pos  = (const float*)d_in[5];
  const float* ln0g = (const float*)d_in[6];
  const float* ln0b = (const float*)d_in[7];
  const float* wq   = (const float*)d_in[8];
  const float* bq   = (const float*)d_in[9];
  const float* wk   = (const float*)d_in[10];
  const float* bk   = (const float*)d_in[11];
  const float* wv   = (const float*)d_in[12];
  const float* bv   = (const float*)d_in[13];
  const float* wo   = (const float*)d_in[14];
  const float* bo   = (const float*)d_in[15];
  const float* ln1g = (const float*)d_in[16];
  const float* ln1b = (const float*)d_in[17];
  const float* w1   = (const float*)d_in[18];
  const float* b1   = (const float*)d_in[19];
  const float* w2   = (const float*)d_in[20];
  const float* b2   = (const float*)d_in[21];
  const float* ln2g = (const float*)d_in[22];
  const float* ln2b = (const float*)d_in[23];
  const float* ex   = (const float*)d_in[24];
  float* out = (float*)d_out;

  char* basep = (char*)d_ws;
  size_t off = 0;
  auto alloc = [&](size_t bytes) -> void* {
    void* p = basep + off;
    off = (off + bytes + 255) & ~(size_t)255;
    return p;
  };
  u16*   xb   = (u16*)alloc((size_t)NTOK * DD * 2);
  u16*   kb   = (u16*)alloc((size_t)NTOK * DD * 2);
  u16*   vb   = (u16*)alloc((size_t)NTOK * DD * 2);
  u16*   wkT  = (u16*)alloc((size_t)DD * DD * 2);
  u16*   wvT  = (u16*)alloc((size_t)DD * DD * 2);
  float* qg   = (float*)alloc(4 * DD * 4);
  float* oacc = (float*)alloc(4 * DD * 4);
  float* x1   = (float*)alloc(4 * DD * 4);
  float* og   = (float*)alloc(4 * DD * 4);
  float* f1a  = (float*)alloc(4 * FF * 4);
  float* f2a  = (float*)alloc(4 * DD * 4);
  float* hws  = (float*)alloc(4 * DD * 4);
  float* part = (float*)alloc((size_t)4 * HH * 16 * 66 * 4);
  int*   gidx = (int*)alloc(64);

  transcvt<<<dim3(24, 24), 256, 0, stream>>>(wk, wkT);
  transcvt<<<dim3(24, 24), 256, 0, stream>>>(wv, wvT);
  seed_k<<<1, 256, 0, stream>>>(sp, ep, bq, bo, b1, b2, qg, oacc, f1a, f2a, gidx);
  embed_ln_k<<<NTOK, 256, 0, stream>>>(sent, emb, pos, ln0g, ln0b, xb);
  gemm_bias<<<dim3(64, 6), 256, 0, stream>>>(xb, wkT, bk, kb);
  gemm_bias<<<dim3(64, 6), 256, 0, stream>>>(xb, wvT, bv, vb);
  matvec4<<<dim3(3, 12), 256, 0, stream>>>(wq, nullptr, xb, gidx, qg, DD, DD, 64, 1);
  gattn_part<<<dim3(16, HH, 4), 256, 0, stream>>>(kb, vb, qg, sent, part);
  gattn_comb<<<dim3(HH, 4), 64, 0, stream>>>(part, og);
  matvec4<<<dim3(3, 12), 256, 0, stream>>>(wo, og, nullptr, nullptr, oacc, DD, DD, 64, 0);
  ln4_k<<<4, 256, 0, stream>>>(xb, gidx, nullptr, oacc, ln1g, ln1b, x1);
  matvec4<<<dim3(12, 12), 256, 0, stream>>>(w1, x1, nullptr, nullptr, f1a, DD, FF, 64, 0);
  matvec4<<<dim3(3, 24), 256, 0, stream>>>(w2, f1a, nullptr, nullptr, f2a, FF, DD, 128, 2);
  ln4_k<<<4, 256, 0, stream>>>(nullptr, nullptr, x1, f2a, ln2g, ln2b, hws);
  logits_k<<<128, 256, 0, stream>>>(hws, ex, out);
  loss_k<<<1, 128, 0, stream>>>(out, lab, out);
}

// Round 3
// 112.318 us; speedup vs baseline: 1.2125x; 1.2125x over previous
//
#include <hip/hip_runtime.h>

typedef unsigned short u16;
typedef unsigned int   u32;
typedef __attribute__((ext_vector_type(8))) short bf16x8;
typedef __attribute__((ext_vector_type(4))) float f32x4;

#define BB 2
#define SS 4096
#define DD 768
#define HH 12
#define FF 3072
#define NTOK 8192

#define GLDS16(gp, lp) __builtin_amdgcn_global_load_lds(                      \
    (const __attribute__((address_space(1))) u32*)(gp),                       \
    (__attribute__((address_space(3))) u32*)(lp), 16, 0, 0)

__device__ __forceinline__ float bf2f(u16 u) {
  u32 x = ((u32)u) << 16;
  return __uint_as_float(x);
}
__device__ __forceinline__ u16 f2bf(float f) {
  u32 x = __float_as_uint(f);
  x = x + 0x7FFFu + ((x >> 16) & 1u);
  return (u16)(x >> 16);
}
__device__ __forceinline__ float gelu_f(float v) {
  return 0.5f * v * (1.0f + erff(v * 0.70710678118654752f));
}

template<bool MAXOP>
__device__ __forceinline__ float blk_reduce(float v, float* sbuf) {
  #pragma unroll
  for (int o = 32; o > 0; o >>= 1) {
    float t = __shfl_xor(v, o, 64);
    v = MAXOP ? fmaxf(v, t) : (v + t);
  }
  int wave = threadIdx.x >> 6;
  int nw = blockDim.x >> 6;
  __syncthreads();
  if ((threadIdx.x & 63) == 0) sbuf[wave] = v;
  __syncthreads();
  float r = sbuf[0];
  for (int i = 1; i < nw; i++) r = MAXOP ? fmaxf(r, sbuf[i]) : (r + sbuf[i]);
  return r;
}

// ---- transpose + f32->bf16 convert for wk and wv in one launch ----
__global__ __launch_bounds__(256) void transcvt2(const float* __restrict__ wk,
    const float* __restrict__ wv, u16* __restrict__ wkT, u16* __restrict__ wvT) {
  const float* W = blockIdx.z ? wv : wk;
  u16* WT = blockIdx.z ? wvT : wkT;
  __shared__ float t[32][33];
  int n0 = blockIdx.x * 32, k0 = blockIdx.y * 32;
  int tx = threadIdx.x & 31, ty = threadIdx.x >> 5; // 32x8
  #pragma unroll
  for (int i = 0; i < 32; i += 8)
    t[ty + i][tx] = W[(size_t)(k0 + ty + i) * DD + n0 + tx];
  __syncthreads();
  #pragma unroll
  for (int i = 0; i < 32; i += 8)
    WT[(size_t)(n0 + ty + i) * DD + k0 + tx] = f2bf(t[tx][ty + i]);
}

// ---- seed accumulators with biases, build gidx (GLOBAL token rows: b*S + s) ----
__global__ void seed_k(const int* sp, const int* ep, const float* bq, const float* bo,
                       const float* b1, const float* b2,
                       float* qg, float* oa, float* f1, float* f2, int* gidx) {
  int tid = threadIdx.x;
  if (tid < 4) {
    int b = tid >> 1;
    int s = (tid & 1) ? ep[b] : sp[b];
    gidx[tid] = b * SS + s;
  }
  for (int i = tid; i < DD; i += 256) {
    float vq = bq[i], vo = bo[i], v2 = b2[i];
    #pragma unroll
    for (int r = 0; r < 4; r++) {
      qg[r * DD + i] = vq; oa[r * DD + i] = vo; f2[r * DD + i] = v2;
    }
  }
  for (int i = tid; i < FF; i += 256) {
    float v1 = b1[i];
    #pragma unroll
    for (int r = 0; r < 4; r++) f1[r * FF + i] = v1;
  }
}

// ---- x = LN(emb[sent] + pos) -> bf16, one block per token, float4 loads ----
__global__ __launch_bounds__(192) void embed_ln_k(const int* __restrict__ sent,
    const float* __restrict__ emb, const float* __restrict__ pos,
    const float* __restrict__ g, const float* __restrict__ be, u16* __restrict__ xout) {
  __shared__ float sbuf[8];
  int tok = blockIdx.x;
  int s = tok & (SS - 1);
  int row = sent[tok];
  int tid = threadIdx.x;
  float4 e = *(const float4*)(emb + (size_t)row * DD + tid * 4);
  float4 p = *(const float4*)(pos + (size_t)s * DD + tid * 4);
  float v0 = e.x + p.x, v1 = e.y + p.y, v2 = e.z + p.z, v3 = e.w + p.w;
  float sum = v0 + v1 + v2 + v3;
  float sq  = v0 * v0 + v1 * v1 + v2 * v2 + v3 * v3;
  sum = blk_reduce<false>(sum, sbuf);
  sq  = blk_reduce<false>(sq, sbuf);
  float mean = sum * (1.f / DD);
  float var  = sq * (1.f / DD) - mean * mean;
  float rstd = rsqrtf(var + 1e-5f);
  float4 gg = *(const float4*)(g + tid * 4);
  float4 bb = *(const float4*)(be + tid * 4);
  float o0 = (v0 - mean) * rstd * gg.x + bb.x;
  float o1 = (v1 - mean) * rstd * gg.y + bb.y;
  float o2 = (v2 - mean) * rstd * gg.z + bb.z;
  float o3 = (v3 - mean) * rstd * gg.w + bb.w;
  u32 lo = (u32)f2bf(o0) | ((u32)f2bf(o1) << 16);
  u32 hi = (u32)f2bf(o2) | ((u32)f2bf(o3) << 16);
  uint2 st; st.x = lo; st.y = hi;
  *(uint2*)(xout + (size_t)tok * DD + tid * 4) = st;
}

// ---- fused K+V projection: m97-style (global_load_lds, linear LDS, 2-barrier) ----
// grid (64, 12): by<6 -> wkT->kb ; by>=6 -> wvT->vb
__global__ __launch_bounds__(256) void gemm_kv(const u16* __restrict__ A,
    const u16* __restrict__ wkT, const u16* __restrict__ wvT,
    const float* __restrict__ bkp, const float* __restrict__ bvp,
    u16* __restrict__ kb, u16* __restrict__ vb) {
  const int K = DD, N = DD;
  __shared__ u16 As[128 * 32];
  __shared__ u16 Bs[128 * 32];
  int which = blockIdx.y >= 6;
  int m0 = blockIdx.x * 128;
  int n0 = (blockIdx.y - (which ? 6 : 0)) * 128;
  const u16* Bt = which ? wvT : wkT;
  const float* bias = which ? bvp : bkp;
  u16* C = which ? vb : kb;
  int tid = threadIdx.x;
  int lane = tid & 63, wave = tid >> 6;
  int wr = wave >> 1, wc = wave & 1;
  f32x4 acc[4][4] = {};
  // staging: tile 128x32 u16 = 8KB = 512 x 16B chunks; chunk = s*256 + wave*64 + lane
  // row = chunk>>2, sub = chunk&3; lds byte off = chunk*16 (linear row-major, pitch 32 u16)
  int ch0 = wave * 64 + lane;
  int r0 = ch0 >> 2, su0 = ch0 & 3;
  int ch1 = 256 + ch0;
  int r1 = ch1 >> 2, su1 = ch1 & 3;
  const u16* a0p = A  + (size_t)(m0 + r0) * K + su0 * 8;
  const u16* a1p = A  + (size_t)(m0 + r1) * K + su1 * 8;
  const u16* b0p = Bt + (size_t)(n0 + r0) * K + su0 * 8;
  const u16* b1p = Bt + (size_t)(n0 + r1) * K + su1 * 8;
  u16* AsW0 = As + (size_t)(wave * 64) * 8;        // wave-uniform LDS bases
  u16* AsW1 = As + (size_t)(256 + wave * 64) * 8;
  u16* BsW0 = Bs + (size_t)(wave * 64) * 8;
  u16* BsW1 = Bs + (size_t)(256 + wave * 64) * 8;
  int fr = lane & 15, fk = (lane >> 4) * 8;
  for (int k0 = 0; k0 < K; k0 += 32) {
    GLDS16(a0p + k0, AsW0);
    GLDS16(a1p + k0, AsW1);
    GLDS16(b0p + k0, BsW0);
    GLDS16(b1p + k0, BsW1);
    __syncthreads();
    bf16x8 af[4], bfr[4];
    #pragma unroll
    for (int i = 0; i < 4; i++)
      af[i] = *(const bf16x8*)(As + ((wr * 64 + i * 16 + fr) << 5) + fk);
    #pragma unroll
    for (int j = 0; j < 4; j++)
      bfr[j] = *(const bf16x8*)(Bs + ((wc * 64 + j * 16 + fr) << 5) + fk);
    #pragma unroll
    for (int i = 0; i < 4; i++)
      #pragma unroll
      for (int j = 0; j < 4; j++)
        acc[i][j] = __builtin_amdgcn_mfma_f32_16x16x32_bf16(af[i], bfr[j], acc[i][j], 0, 0, 0);
    __syncthreads();
  }
  int cr = (lane >> 4) * 4;
  int cc = lane & 15;
  #pragma unroll
  for (int i = 0; i < 4; i++) {
    #pragma unroll
    for (int j = 0; j < 4; j++) {
      int col = n0 + wc * 64 + j * 16 + cc;
      float bvv = bias[col];
      int rowb = m0 + wr * 64 + i * 16 + cr;
      #pragma unroll
      for (int r = 0; r < 4; r++) {
        float v = acc[i][j][r] + bvv;
        C[(size_t)(rowb + r) * N + col] = f2bf(v);
      }
    }
  }
}

// ---- generic 4-row batched matvec, split-K atomics: acc[r,n] += sum_k in[r,k]*W[k,n] ----
__global__ __launch_bounds__(256) void matvec4(const float* __restrict__ W,
    const float* __restrict__ inF, const u16* __restrict__ inB, const int* __restrict__ gidx,
    float* __restrict__ acc, int K, int N, int kchunk, int mode) {
  __shared__ float s_in[4 * 256];
  int n = blockIdx.x * 256 + threadIdx.x;
  int k0 = blockIdx.y * kchunk;
  for (int idx = threadIdx.x; idx < 4 * kchunk; idx += 256) {
    int r = idx / kchunk, kk = idx - r * kchunk;
    float vv;
    if (mode == 1) vv = bf2f(inB[(size_t)gidx[r] * K + k0 + kk]);
    else vv = inF[(size_t)r * K + k0 + kk];
    if (mode == 2) vv = gelu_f(vv);
    s_in[r * 256 + kk] = vv;
  }
  __syncthreads();
  float a0 = 0.f, a1 = 0.f, a2 = 0.f, a3 = 0.f;
  for (int kk = 0; kk < kchunk; kk++) {
    float w = W[(size_t)(k0 + kk) * N + n];
    a0 += s_in[kk] * w;
    a1 += s_in[256 + kk] * w;
    a2 += s_in[512 + kk] * w;
    a3 += s_in[768 + kk] * w;
  }
  atomicAdd(&acc[n], a0);
  atomicAdd(&acc[N + n], a1);
  atomicAdd(&acc[2 * N + n], a2);
  atomicAdd(&acc[3 * N + n], a3);
}

// ---- global attention partial, coalesced: 8 lanes/row x 8 chunks ----
__global__ __launch_bounds__(256) void gattn_part(const u16* __restrict__ kb,
    const u16* __restrict__ vb, const float* __restrict__ qg, const int* __restrict__ sent,
    float* __restrict__ part) {
  int sc = blockIdx.x, h = blockIdx.y, bg = blockIdx.z;
  int b = bg >> 1;
  __shared__ float pbuf[256];
  __shared__ float ovs[32][64];
  __shared__ float sbuf[8];
  int tid = threadIdx.x;
  int rsub = tid >> 3, csub = tid & 7;      // 32 row-groups x 8 d-chunks
  float qr[8];
  #pragma unroll
  for (int j = 0; j < 8; j++) qr[j] = qg[bg * DD + h * 64 + csub * 8 + j];
  size_t kbase = ((size_t)b * SS + sc * 256) * DD + h * 64 + csub * 8;
  // scores: 8 passes of 32 rows
  #pragma unroll
  for (int pass = 0; pass < 8; pass++) {
    int rowi = pass * 32 + rsub;
    uint4 u = *(const uint4*)(kb + kbase + (size_t)rowi * DD);
    u32 vals[4] = {u.x, u.y, u.z, u.w};
    float dot = 0.f;
    #pragma unroll
    for (int t = 0; t < 4; t++) {
      dot += qr[t * 2]     * __uint_as_float(vals[t] << 16);
      dot += qr[t * 2 + 1] * __uint_as_float(vals[t] & 0xFFFF0000u);
    }
    dot += __shfl_xor(dot, 1, 64);
    dot += __shfl_xor(dot, 2, 64);
    dot += __shfl_xor(dot, 4, 64);
    if (csub == 0) pbuf[rowi] = dot;
  }
  __syncthreads();
  float score = (sent[b * SS + sc * 256 + tid] != 1) ? pbuf[tid] * 0.125f : -1e9f;
  float m = blk_reduce<true>(score, sbuf);
  float p = expf(score - m);
  float psum = blk_reduce<false>(p, sbuf);
  pbuf[tid] = p;
  __syncthreads();
  // PV: same access pattern on vb, accumulate 8 d-elems over 256 rows
  float a[8] = {0.f, 0.f, 0.f, 0.f, 0.f, 0.f, 0.f, 0.f};
  #pragma unroll
  for (int pass = 0; pass < 8; pass++) {
    int rowi = pass * 32 + rsub;
    uint4 u = *(const uint4*)(vb + kbase + (size_t)rowi * DD);
    u32 vals[4] = {u.x, u.y, u.z, u.w};
    float pw = pbuf[rowi];
    #pragma unroll
    for (int t = 0; t < 4; t++) {
      a[t * 2]     += pw * __uint_as_float(vals[t] << 16);
      a[t * 2 + 1] += pw * __uint_as_float(vals[t] & 0xFFFF0000u);
    }
  }
  #pragma unroll
  for (int j = 0; j < 8; j++) ovs[rsub][csub * 8 + j] = a[j];
  __syncthreads();
  float* pp = part + (((size_t)bg * HH + h) * 16 + sc) * 66;
  if (tid == 0) { pp[0] = m; pp[1] = psum; }
  if (tid < 64) {
    float o = 0.f;
    #pragma unroll
    for (int g2 = 0; g2 < 32; g2++) o += ovs[g2][tid];
    pp[2 + tid] = o;
  }
}

// ---- wo matvec with fused softmax-combine (blockIdx.y == head) ----
__global__ __launch_bounds__(256) void matvec_wo(const float* __restrict__ W,
    const float* __restrict__ part, float* __restrict__ acc) {
  __shared__ float s_in[4][64];
  int h = blockIdx.y;
  int tid = threadIdx.x;
  int bg = tid >> 6, d = tid & 63;
  const float* pp = part + (((size_t)bg * HH + h) * 16) * 66;
  float M = -1e30f;
  for (int c = 0; c < 16; c++) M = fmaxf(M, pp[c * 66]);
  float Ssum = 0.f, o = 0.f;
  for (int c = 0; c < 16; c++) {
    float e = expf(pp[c * 66] - M);
    Ssum += pp[c * 66 + 1] * e;
    o += pp[c * 66 + 2 + d] * e;
  }
  s_in[bg][d] = o / Ssum;
  __syncthreads();
  int n = blockIdx.x * 256 + tid;
  int k0 = h * 64;
  float a0 = 0.f, a1 = 0.f, a2 = 0.f, a3 = 0.f;
  for (int kk = 0; kk < 64; kk++) {
    float w = W[(size_t)(k0 + kk) * DD + n];
    a0 += s_in[0][kk] * w;
    a1 += s_in[1][kk] * w;
    a2 += s_in[2][kk] * w;
    a3 += s_in[3][kk] * w;
  }
  atomicAdd(&acc[n], a0);
  atomicAdd(&acc[DD + n], a1);
  atomicAdd(&acc[2 * DD + n], a2);
  atomicAdd(&acc[3 * DD + n], a3);
}

// ---- 4-row layernorm: out[r] = LN(in1 + in2)  (in1 = bf16 x[gidx[r]] or f32 rows) ----
__global__ __launch_bounds__(256) void ln4_k(const u16* __restrict__ xb, const int* __restrict__ gidx,
    const float* __restrict__ in1f, const float* __restrict__ in2,
    const float* __restrict__ g, const float* __restrict__ be, float* __restrict__ outp) {
  __shared__ float sbuf[8];
  int r = blockIdx.x;
  float v[3];
  float sum = 0.f, sq = 0.f;
  #pragma unroll
  for (int i = 0; i < 3; i++) {
    int d = threadIdx.x + i * 256;
    float t;
    if (xb) t = bf2f(xb[(size_t)gidx[r] * DD + d]);
    else    t = in1f[r * DD + d];
    t += in2[r * DD + d];
    v[i] = t; sum += t; sq += t * t;
  }
  sum = blk_reduce<false>(sum, sbuf);
  sq  = blk_reduce<false>(sq, sbuf);
  float mean = sum * (1.f / DD);
  float var  = sq * (1.f / DD) - mean * mean;
  float rstd = rsqrtf(var + 1e-5f);
  #pragma unroll
  for (int i = 0; i < 3; i++) {
    int d = threadIdx.x + i * 256;
    outp[r * DD + d] = (v[i] - mean) * rstd * g[d] + be[d];
  }
}

// ---- logits[b,j] = mention[b] . ex[j], one block per j ----
__global__ __launch_bounds__(256) void logits_k(const float* __restrict__ hws,
    const float* __restrict__ ex, float* __restrict__ out) {
  __shared__ float sbuf[8];
  int j = blockIdx.x;
  const float* er = ex + (size_t)j * 1536;
  float d0 = 0.f, d1 = 0.f;
  for (int c = threadIdx.x; c < 768; c += 256) {
    float e0 = er[c], e1 = er[768 + c];
    d0 += hws[c] * e0 + hws[768 + c] * e1;
    d1 += hws[1536 + c] * e0 + hws[2304 + c] * e1;
  }
  d0 = blk_reduce<false>(d0, sbuf);
  d1 = blk_reduce<false>(d1, sbuf);
  if (threadIdx.x == 0) { out[j] = d0; out[128 + j] = d1; }
}

// ---- loss = -sum_b logsoftmax(logits[b])[label_b] ----
__global__ __launch_bounds__(128) void loss_k(const float* __restrict__ lg,
    const int* __restrict__ labels, float* __restrict__ out) {
  __shared__ float sbuf[8];
  int tid = threadIdx.x; // 128
  float v0 = lg[tid], v1 = lg[128 + tid];
  float m0 = blk_reduce<true>(v0, sbuf);
  float m1 = blk_reduce<true>(v1, sbuf);
  float s0 = blk_reduce<false>(expf(v0 - m0), sbuf);
  float s1 = blk_reduce<false>(expf(v1 - m1), sbuf);
  if (tid == 0) {
    float lp0 = lg[labels[0]] - m0 - logf(s0);
    float lp1 = lg[128 + labels[1]] - m1 - logf(s1);
    out[256] = -(lp0 + lp1);
  }
}

extern "C" void kernel_launch(void* const* d_in, const int* in_sizes, int n_in,
                              void* d_out, int out_size, void* d_ws, size_t ws_size,
                              hipStream_t stream) {
  const int*   sent = (const int*)d_in[0];
  const int*   sp   = (const int*)d_in[1];
  const int*   ep   = (const int*)d_in[2];
  const int*   lab  = (const int*)d_in[3];
  const float* emb  = (const float*)d_in[4];
  const float* pos  = (const float*)d_in[5];
  const float* ln0g = (const float*)d_in[6];
  const float* ln0b = (const float*)d_in[7];
  const float* wq   = (const float*)d_in[8];
  const float* bq   = (const float*)d_in[9];
  const float* wk   = (const float*)d_in[10];
  const float* bk   = (const float*)d_in[11];
  const float* wv   = (const float*)d_in[12];
  const float* bv   = (const float*)d_in[13];
  const float* wo   = (const float*)d_in[14];
  const float* bo   = (const float*)d_in[15];
  const float* ln1g = (const float*)d_in[16];
  const float* ln1b = (const float*)d_in[17];
  const float* w1   = (const float*)d_in[18];
  const float* b1   = (const float*)d_in[19];
  const float* w2   = (const float*)d_in[20];
  const float* b2   = (const float*)d_in[21];
  const float* ln2g = (const float*)d_in[22];
  const float* ln2b = (const float*)d_in[23];
  const float* ex   = (const float*)d_in[24];
  float* out = (float*)d_out;

  char* basep = (char*)d_ws;
  size_t off = 0;
  auto alloc = [&](size_t bytes) -> void* {
    void* p = basep + off;
    off = (off + bytes + 255) & ~(size_t)255;
    return p;
  };
  u16*   xb   = (u16*)alloc((size_t)NTOK * DD * 2);
  u16*   kb   = (u16*)alloc((size_t)NTOK * DD * 2);
  u16*   vb   = (u16*)alloc((size_t)NTOK * DD * 2);
  u16*   wkT  = (u16*)alloc((size_t)DD * DD * 2);
  u16*   wvT  = (u16*)alloc((size_t)DD * DD * 2);
  float* qg   = (float*)alloc(4 * DD * 4);
  float* oacc = (float*)alloc(4 * DD * 4);
  float* x1   = (float*)alloc(4 * DD * 4);
  float* f1a  = (float*)alloc(4 * FF * 4);
  float* f2a  = (float*)alloc(4 * DD * 4);
  float* hws  = (float*)alloc(4 * DD * 4);
  float* part = (float*)alloc((size_t)4 * HH * 16 * 66 * 4);
  int*   gidx = (int*)alloc(64);

  transcvt2<<<dim3(24, 24, 2), 256, 0, stream>>>(wk, wv, wkT, wvT);
  seed_k<<<1, 256, 0, stream>>>(sp, ep, bq, bo, b1, b2, qg, oacc, f1a, f2a, gidx);
  embed_ln_k<<<NTOK, 192, 0, stream>>>(sent, emb, pos, ln0g, ln0b, xb);
  gemm_kv<<<dim3(64, 12), 256, 0, stream>>>(xb, wkT, wvT, bk, bv, kb, vb);
  matvec4<<<dim3(3, 12), 256, 0, stream>>>(wq, nullptr, xb, gidx, qg, DD, DD, 64, 1);
  gattn_part<<<dim3(16, HH, 4), 256, 0, stream>>>(kb, vb, qg, sent, part);
  matvec_wo<<<dim3(3, 12), 256, 0, stream>>>(wo, part, oacc);
  ln4_k<<<4, 256, 0, stream>>>(xb, gidx, nullptr, oacc, ln1g, ln1b, x1);
  matvec4<<<dim3(12, 12), 256, 0, stream>>>(w1, x1, nullptr, nullptr, f1a, DD, FF, 64, 0);
  matvec4<<<dim3(3, 24), 256, 0, stream>>>(w2, f1a, nullptr, nullptr, f2a, FF, DD, 128, 2);
  ln4_k<<<4, 256, 0, stream>>>(nullptr, nullptr, x1, f2a, ln2g, ln2b, hws);
  logits_k<<<128, 256, 0, stream>>>(hws, ex, out);
  loss_k<<<1, 128, 0, stream>>>(out, lab, out);
}